// Round 8
// baseline (310.476 us; speedup 1.0000x reference)
//
#include <hip/hip_runtime.h>
#include <hip/hip_bf16.h>
#include <cstdint>

#define BB   2
#define SS   1024
#define HIDD 768
#define NH   12
#define DH   64
#define BH   (BB*NH)   // 24

typedef short bf16x8 __attribute__((ext_vector_type(8)));
typedef float f32x4  __attribute__((ext_vector_type(4)));
typedef _Float16 f16x8 __attribute__((ext_vector_type(8)));

__device__ __forceinline__ unsigned short f2b(float x) {
    union { float f; uint32_t u; } v; v.f = x;
    uint32_t u = v.u;
    uint32_t r = (u + 0x7fffu + ((u >> 16) & 1u)) >> 16;
    return (unsigned short)r;
}

__device__ __forceinline__ void async16(const void* g, void* l) {
    __builtin_amdgcn_global_load_lds(
        (const __attribute__((address_space(1))) unsigned int*)g,
        (__attribute__((address_space(3))) unsigned int*)l,
        16, 0, 0);
}

// ---------------- kernel 0 (optional): fuse bias streams ----------------
// Bh[bh][s][k] = fp16( (rel + rel_2d) * 0.125 + amask[b][k] )
// Rationale: across v0-v7 the flash kernel's bias consumption is pinned at
// ~2 TB/s regardless of granule (256B/1KB), occupancy (8-35%), staging
// (LDS/reg/direct), locality (XCD swizzle) -> per-byte pattern cap.
// Compression is the only lever that scales with that cap: read the 201 MB
// ONCE coalesced here (~6 TB/s regime), emit 50 MB fp16 for flash.
__global__ __launch_bounds__(256) void prep_bias(
    const float* __restrict__ rel, const float* __restrict__ rel2d,
    const float* __restrict__ amask, _Float16* __restrict__ Bh) {
    const size_t nchunk = (size_t)BH * SS * SS / 8;   // 8 elems per chunk
    for (size_t i = blockIdx.x * 256 + threadIdx.x; i < nchunk;
         i += (size_t)gridDim.x * 256) {
        const size_t e = i * 8;
        const int bh = (int)(i >> 17);                 // SS*SS/8 = 2^17 chunks per bh
        const int b  = (bh >= NH) ? 1 : 0;
        const int k8 = ((int)i & 127) * 8;             // k offset within row
        const float4* r1 = (const float4*)(rel + e);
        const float4* r2 = (const float4*)(rel2d + e);
        const float4* mp = (const float4*)(amask + (size_t)b * SS + k8);
        float4 a0 = r1[0], a1 = r1[1];
        float4 c0 = r2[0], c1 = r2[1];
        float4 m0 = mp[0], m1 = mp[1];
        f16x8 o;
        o[0] = (_Float16)((a0.x + c0.x) * 0.125f + m0.x);
        o[1] = (_Float16)((a0.y + c0.y) * 0.125f + m0.y);
        o[2] = (_Float16)((a0.z + c0.z) * 0.125f + m0.z);
        o[3] = (_Float16)((a0.w + c0.w) * 0.125f + m0.w);
        o[4] = (_Float16)((a1.x + c1.x) * 0.125f + m1.x);
        o[5] = (_Float16)((a1.y + c1.y) * 0.125f + m1.y);
        o[6] = (_Float16)((a1.z + c1.z) * 0.125f + m1.z);
        o[7] = (_Float16)((a1.w + c1.w) * 0.125f + m1.w);
        *(f16x8*)(Bh + e) = o;
    }
}

// ---------------- kernel 1: hidden_states fp32 -> bf16 ----------------
__global__ void cvt_x(const float* __restrict__ x, unsigned short* __restrict__ xb) {
    int i = blockIdx.x * blockDim.x + threadIdx.x;   // one float4 per thread
    float4 v = ((const float4*)x)[i];
    ushort4 o;
    o.x = f2b(v.x); o.y = f2b(v.y); o.z = f2b(v.z); o.w = f2b(v.w);
    ((ushort4*)xb)[i] = o;
}

// ------------- kernel 2: W [k][n] fp32 -> Wt [n][k] bf16 (q|k|v) -------------
__global__ void transpose_w(const float* __restrict__ Wq, const float* __restrict__ Wk,
                            const float* __restrict__ Wv, unsigned short* __restrict__ Wt) {
    __shared__ float tile[32][33];
    const int w = blockIdx.z;
    const float* W = (w == 0) ? Wq : (w == 1) ? Wk : Wv;
    const int tx = threadIdx.x & 31, ty = threadIdx.x >> 5;   // 32 x 8
    const int k0 = blockIdx.x * 32, n0 = blockIdx.y * 32;
    for (int p = 0; p < 4; ++p)
        tile[ty + p * 8][tx] = W[(k0 + ty + p * 8) * HIDD + n0 + tx];
    __syncthreads();
    for (int p = 0; p < 4; ++p) {
        int n = n0 + ty + p * 8;
        Wt[(w * HIDD + n) * HIDD + k0 + tx] = f2b(tile[tx][ty + p * 8]);
    }
}

// ------------- kernel 3: QKV GEMM 2048x2304x768, bf16 MFMA -------------
__global__ __launch_bounds__(256) void qkv_gemm(
    const unsigned short* __restrict__ Xb, const unsigned short* __restrict__ Wt,
    const float* __restrict__ bq, const float* __restrict__ bk, const float* __restrict__ bv,
    unsigned short* __restrict__ Qh, unsigned short* __restrict__ Kh,
    unsigned short* __restrict__ Vh) {
    __shared__ __align__(16) unsigned short lA[2][128 * 32];
    __shared__ __align__(16) unsigned short lB[2][64 * 32];
    const int t = threadIdx.x;
    const int wave = t >> 6, lane = t & 63;
    const int l15 = lane & 15, quad = lane >> 4;
    const int m0 = blockIdx.x * 128;
    const int n0 = blockIdx.y * 64;
    const int wm = wave * 32;

    f32x4 acc[2][4] = {};

    auto stage = [&](int k0, int b) {
        #pragma unroll
        for (int r = 0; r < 2; ++r) {
            int ci = r * 256 + t;
            async16(Xb + (m0 + (ci >> 2)) * HIDD + k0 + (ci & 3) * 8,
                    &lA[b][(r * 256 + wave * 64) * 8]);
        }
        async16(Wt + (n0 + (t >> 2)) * HIDD + k0 + (t & 3) * 8,
                &lB[b][(wave * 64) * 8]);
    };

    stage(0, 0);
    for (int ki = 0; ki < 24; ++ki) {
        const int cur = ki & 1;
        __syncthreads();
        if (ki < 23) stage((ki + 1) * 32, cur ^ 1);
        bf16x8 af[2], bf[4];
        #pragma unroll
        for (int i = 0; i < 2; ++i)
            af[i] = *(const bf16x8*)&lA[cur][(wm + i * 16 + l15) * 32 + quad * 8];
        #pragma unroll
        for (int j = 0; j < 4; ++j)
            bf[j] = *(const bf16x8*)&lB[cur][(j * 16 + l15) * 32 + quad * 8];
        #pragma unroll
        for (int i = 0; i < 2; ++i)
            #pragma unroll
            for (int j = 0; j < 4; ++j)
                acc[i][j] = __builtin_amdgcn_mfma_f32_16x16x32_bf16(af[i], bf[j], acc[i][j], 0, 0, 0);
    }

    const int sect = (n0 >= 1536) ? 2 : (n0 >= 768) ? 1 : 0;
    const float* bias = (sect == 0) ? bq : (sect == 1) ? bk : bv;
    unsigned short* dst = (sect == 0) ? Qh : (sect == 1) ? Kh : Vh;
    const float scale = (sect == 0) ? 0.125f : 1.0f;
    #pragma unroll
    for (int i = 0; i < 2; ++i) {
        #pragma unroll
        for (int j = 0; j < 4; ++j) {
            int n  = n0 + j * 16 + l15;
            int nn = n - sect * HIDD;
            int h = nn >> 6, d = nn & 63;
            float bval = bias[nn];
            #pragma unroll
            for (int r = 0; r < 4; ++r) {
                int m = m0 + wm + i * 16 + quad * 4 + r;
                int b = m >> 10, s = m & 1023;
                float v = (acc[i][j][r] + bval) * scale;
                dst[((size_t)(b * NH + h) * SS + s) * DH + d] = f2b(v);
            }
        }
    }
}

// ------------- kernel 3b: Vh [bh][s][d] -> VhT [bh][d][s] -------------
__global__ __launch_bounds__(256) void transpose_v(
    const unsigned short* __restrict__ Vh, unsigned short* __restrict__ VhT) {
    __shared__ unsigned short tile[64][65];
    const int t = threadIdx.x;
    const int bh = blockIdx.y;
    const int s0 = blockIdx.x * 64;
    const int tx = t & 63, ty = t >> 6;
    const unsigned short* src = Vh + (size_t)bh * SS * DH;
    #pragma unroll
    for (int p = 0; p < 16; ++p)
        tile[ty + p * 4][tx] = src[(size_t)(s0 + ty + p * 4) * DH + tx];
    __syncthreads();
    unsigned short* dst = VhT + (size_t)bh * DH * SS;
    #pragma unroll
    for (int p = 0; p < 16; ++p)
        dst[(size_t)(ty + p * 4) * SS + s0 + tx] = tile[tx][ty + p * 4];
}

// ------------- kernel 4a: flash attention, fp16 fused-bias -------------
// v0 structure (proven 94us; 3 blocks/CU, LDS 53760) with the bias source
// swapped to the fused fp16 Bh: 4x fewer bias bytes. Bias staged per
// 2-tile GROUP (128 keys): 4 async16 per wave per group, double-buffered
// per wave (2 x 4 KB). Mask + (*0.125+mk) folded into prep. Group drains
// ride the end-of-iteration vmcnt(0) of odd tiles; even-tile ends use
// vmcnt(4) to keep the next group in flight across the barrier.
__global__ __launch_bounds__(128) void flash_attn_pb(
    const unsigned short* __restrict__ Qh, const unsigned short* __restrict__ Kh,
    const unsigned short* __restrict__ VhT, const _Float16* __restrict__ Bh,
    const float* __restrict__ hmask, float* __restrict__ out) {
    // [0,16384)      lK[2] (2 x 64x64 bf16, swizzled)
    // [16384,32768)  lV[2]
    // [32768,49152)  bias: wave w at +w*8192, group buf gb at +gb*4096
    // [49152,53760)  P: wave w at +w*2304B (16x72 bf16)
    __shared__ __align__(16) char smemraw[53760];

    const int t = threadIdx.x;
    const int wave = t >> 6, lane = t & 63;
    const int l15 = lane & 15, quad = lane >> 4;
    const int l7 = l15 & 7;
    const int bh = blockIdx.y;
    const int b = bh / NH, h = bh % NH;
    const int m0w = blockIdx.x * 32 + wave * 16;

    const unsigned short* Qp = Qh + (size_t)bh * SS * DH;
    const unsigned short* Kp = Kh + (size_t)bh * SS * DH;
    const unsigned short* Vp = VhT + (size_t)bh * DH * SS;
    const _Float16* Bhp = Bh + (size_t)bh * SS * SS;

    char* biasW = smemraw + 32768 + wave * 8192;
    unsigned short* Pw = (unsigned short*)(smemraw + 49152) + wave * (16 * 72);

    auto stage_kv = [&](int j0, int buf) {
        unsigned short* dK = (unsigned short*)(smemraw + buf * 8192);
        unsigned short* dV = (unsigned short*)(smemraw + 16384 + buf * 8192);
        #pragma unroll
        for (int i = 0; i < 4; ++i) {
            int ci = i * 128 + t;                 // 0..511
            int row = ci >> 3, sc = ci & 7;
            int g = sc ^ (row & 7);               // fetch-side XOR swizzle
            async16(Kp + (size_t)(j0 + row) * DH + g * 8,
                    dK + (i * 128 + wave * 64) * 8);
            async16(Vp + (size_t)row * SS + j0 + g * 8,
                    dV + (i * 128 + wave * 64) * 8);
        }
    };

    // bias group g (keys [g*128, g*128+128)) for this wave's 16 rows into
    // buf gb: 4 async16; LDS lands row-major [16][128] fp16
    // (slot i*4+quad == global row 4i+quad; lane covers 16B of the row).
    auto stage_bias = [&](int g, int gb) {
        char* dst = biasW + gb * 4096;
        #pragma unroll
        for (int i = 0; i < 4; ++i)
            async16(Bhp + (size_t)(m0w + 4 * i + quad) * SS + g * 128 + l15 * 8,
                    dst + i * 1024);
    };

    bf16x8 qf0 = *(const bf16x8*)&Qp[(m0w + l15) * DH + quad * 8];
    bf16x8 qf1 = *(const bf16x8*)&Qp[(m0w + l15) * DH + 32 + quad * 8];

    f32x4 o[4] = {};
    float mrow[4] = {-1e30f, -1e30f, -1e30f, -1e30f};
    float lrow[4] = {0.f, 0.f, 0.f, 0.f};

    stage_kv(0, 0);
    stage_bias(0, 0);
    asm volatile("s_waitcnt vmcnt(0)" ::: "memory");
    __builtin_amdgcn_s_barrier();

    for (int tt = 0; tt < 16; ++tt) {
        const int cur = tt & 1;        // KV buffer
        const int T = tt & 1;          // tile within bias group
        const int g = tt >> 1;         // bias group
        const int j0 = tt * 64;
        const unsigned short* cK = (const unsigned short*)(smemraw + cur * 8192);
        const unsigned short* cV = (const unsigned short*)(smemraw + 16384 + cur * 8192);
        const bool pre_bias = (T == 0) && (tt <= 12);

        // ---- issue next KV tile, then next bias group (even tiles) ----
        if (tt < 15) stage_kv(j0 + 64, cur ^ 1);
        if (pre_bias) stage_bias(g + 1, (g + 1) & 1);

        // ---- QK^T from LDS buf[cur] (guaranteed by previous wait+barrier) ----
        f32x4 sc4[4] = {};
        #pragma unroll
        for (int c = 0; c < 4; ++c) {
            int row = c * 16 + l15;
            bf16x8 k0f = *(const bf16x8*)&cK[row * 64 + (quad ^ l7) * 8];
            bf16x8 k1f = *(const bf16x8*)&cK[row * 64 + ((quad + 4) ^ l7) * 8];
            sc4[c] = __builtin_amdgcn_mfma_f32_16x16x32_bf16(qf0, k0f, sc4[c], 0, 0, 0);
            sc4[c] = __builtin_amdgcn_mfma_f32_16x16x32_bf16(qf1, k1f, sc4[c], 0, 0, 0);
        }

        // ---- bias add from LDS group buf (fp16 -> fp32); group g landed
        // via the vmcnt(0) at the end of iteration tt-1 (or prologue) ----
        const _Float16* bl = (const _Float16*)(biasW + (g & 1) * 4096);
        float sv[4][4];
        #pragma unroll
        for (int c = 0; c < 4; ++c)
            #pragma unroll
            for (int r = 0; r < 4; ++r)
                sv[c][r] = sc4[c][r]
                         + (float)bl[(quad * 4 + r) * 128 + T * 64 + c * 16 + l15];

        // ---- online softmax per row (reg r <-> row quad*4+r) ----
        float alpha[4];
        #pragma unroll
        for (int r = 0; r < 4; ++r) {
            float mx = fmaxf(fmaxf(sv[0][r], sv[1][r]), fmaxf(sv[2][r], sv[3][r]));
            #pragma unroll
            for (int off = 1; off < 16; off <<= 1) mx = fmaxf(mx, __shfl_xor(mx, off, 64));
            float mnew = fmaxf(mrow[r], mx);
            alpha[r] = __expf(mrow[r] - mnew);
            mrow[r] = mnew;
            float rs = 0.f;
            #pragma unroll
            for (int c = 0; c < 4; ++c) {
                float p = __expf(sv[c][r] - mnew);
                sv[c][r] = p;
                rs += p;
            }
            #pragma unroll
            for (int off = 1; off < 16; off <<= 1) rs += __shfl_xor(rs, off, 64);
            lrow[r] = lrow[r] * alpha[r] + rs;
            o[0][r] *= alpha[r]; o[1][r] *= alpha[r]; o[2][r] *= alpha[r]; o[3][r] *= alpha[r];
        }

        // ---- P -> LDS (A-operand layout) ----
        #pragma unroll
        for (int c = 0; c < 4; ++c)
            #pragma unroll
            for (int r = 0; r < 4; ++r)
                Pw[(quad * 4 + r) * 72 + c * 16 + l15] = f2b(sv[c][r]);

        bf16x8 pf0 = *(const bf16x8*)&Pw[l15 * 72 + quad * 8];
        bf16x8 pf1 = *(const bf16x8*)&Pw[l15 * 72 + 32 + quad * 8];

        // ---- O += P . V from LDS buf[cur] ----
        #pragma unroll
        for (int dt = 0; dt < 4; ++dt) {
            int row = dt * 16 + l15;
            bf16x8 v0f = *(const bf16x8*)&cV[row * 64 + (quad ^ l7) * 8];
            bf16x8 v1f = *(const bf16x8*)&cV[row * 64 + ((quad + 4) ^ l7) * 8];
            o[dt] = __builtin_amdgcn_mfma_f32_16x16x32_bf16(pf0, v0f, o[dt], 0, 0, 0);
            o[dt] = __builtin_amdgcn_mfma_f32_16x16x32_bf16(pf1, v1f, o[dt], 0, 0, 0);
        }

        // ---- counted wait + barrier: need KV(t+1) complete.
        // pre_bias iters: issued kv[8] then bias[4] -> vmcnt(4) retires KV
        // fully, keeps the bias group in flight across the barrier.
        // otherwise drain (also retires any in-flight bias group). ----
        if (tt < 15) {
            if (pre_bias) asm volatile("s_waitcnt vmcnt(4)" ::: "memory");
            else          asm volatile("s_waitcnt vmcnt(0)" ::: "memory");
            __builtin_amdgcn_s_barrier();
        }
    }

    // ---- epilogue: each wave owns its rows, no combine ----
    const float hm = hmask[h];
    #pragma unroll
    for (int r = 0; r < 4; ++r) {
        float inv = hm / lrow[r];
        int s = m0w + quad * 4 + r;
        float* op = out + ((size_t)(b * SS + s)) * HIDD + h * DH;
        #pragma unroll
        for (int dt = 0; dt < 4; ++dt) op[dt * 16 + l15] = o[dt][r] * inv;
    }
}

// ------------- kernel 4b: flash attention, v0 (fallback) -------------
__global__ __launch_bounds__(128) void flash_attn_v0(
    const unsigned short* __restrict__ Qh, const unsigned short* __restrict__ Kh,
    const unsigned short* __restrict__ VhT,
    const float* __restrict__ rel, const float* __restrict__ rel2d,
    const float* __restrict__ amask, const float* __restrict__ hmask,
    float* __restrict__ out) {
    __shared__ __align__(16) char smemraw[53760];

    const int t = threadIdx.x;
    const int wave = t >> 6, lane = t & 63;
    const int l15 = lane & 15, quad = lane >> 4;
    const int l7 = l15 & 7;
    const int bh = blockIdx.y;
    const int b = bh / NH, h = bh % NH;
    const int m0w = blockIdx.x * 32 + wave * 16;

    const unsigned short* Qp = Qh + (size_t)bh * SS * DH;
    const unsigned short* Kp = Kh + (size_t)bh * SS * DH;
    const unsigned short* Vp = VhT + (size_t)bh * DH * SS;
    const float* relp  = rel   + (size_t)bh * SS * SS;
    const float* rel2p = rel2d + (size_t)bh * SS * SS;
    const float* maskp = amask + (size_t)b * SS;

    float* stgA = (float*)(smemraw + 32768 + wave * 8192);
    float* stgB = stgA + 1024;
    unsigned short* Pw = (unsigned short*)(smemraw + 49152) + wave * (16 * 72);

    auto stage_kv = [&](int j0, int buf) {
        unsigned short* dK = (unsigned short*)(smemraw + buf * 8192);
        unsigned short* dV = (unsigned short*)(smemraw + 16384 + buf * 8192);
        #pragma unroll
        for (int i = 0; i < 4; ++i) {
            int ci = i * 128 + t;
            int row = ci >> 3, sc = ci & 7;
            int g = sc ^ (row & 7);
            async16(Kp + (size_t)(j0 + row) * DH + g * 8,
                    dK + (i * 128 + wave * 64) * 8);
            async16(Vp + (size_t)row * SS + j0 + g * 8,
                    dV + (i * 128 + wave * 64) * 8);
        }
    };

    auto stage_bias = [&](int j0) {
        #pragma unroll
        for (int i = 0; i < 4; ++i) {
            async16(relp  + (size_t)(m0w + 4 * i + quad) * SS + j0 + l15 * 4,
                    (char*)stgA + i * 1024);
            async16(rel2p + (size_t)(m0w + 4 * i + quad) * SS + j0 + l15 * 4,
                    (char*)stgB + i * 1024);
        }
    };

    bf16x8 qf0 = *(const bf16x8*)&Qp[(m0w + l15) * DH + quad * 8];
    bf16x8 qf1 = *(const bf16x8*)&Qp[(m0w + l15) * DH + 32 + quad * 8];

    f32x4 o[4] = {};
    float mrow[4] = {-1e30f, -1e30f, -1e30f, -1e30f};
    float lrow[4] = {0.f, 0.f, 0.f, 0.f};

    stage_kv(0, 0);
    __syncthreads();

    for (int tt = 0; tt < 16; ++tt) {
        const int j0 = tt * 64, cur = tt & 1;
        const unsigned short* cK = (const unsigned short*)(smemraw + cur * 8192);
        const unsigned short* cV = (const unsigned short*)(smemraw + 16384 + cur * 8192);

        stage_bias(j0);
        if (tt < 15) stage_kv(j0 + 64, cur ^ 1);

        float mk[4];
        #pragma unroll
        for (int c = 0; c < 4; ++c) mk[c] = maskp[j0 + c * 16 + l15];

        f32x4 sc4[4] = {};
        #pragma unroll
        for (int c = 0; c < 4; ++c) {
            int row = c * 16 + l15;
            bf16x8 k0f = *(const bf16x8*)&cK[row * 64 + (quad ^ l7) * 8];
            bf16x8 k1f = *(const bf16x8*)&cK[row * 64 + ((quad + 4) ^ l7) * 8];
            sc4[c] = __builtin_amdgcn_mfma_f32_16x16x32_bf16(qf0, k0f, sc4[c], 0, 0, 0);
            sc4[c] = __builtin_amdgcn_mfma_f32_16x16x32_bf16(qf1, k1f, sc4[c], 0, 0, 0);
        }

        if (tt < 15) { asm volatile("s_waitcnt vmcnt(8)" ::: "memory"); }
        else         { asm volatile("s_waitcnt vmcnt(0)" ::: "memory"); }

        float sv[4][4];
        #pragma unroll
        for (int c = 0; c < 4; ++c)
            #pragma unroll
            for (int r = 0; r < 4; ++r) {
                int fi = (quad * 4 + r) * 64 + c * 16 + l15;
                sv[c][r] = sc4[c][r] + (stgA[fi] + stgB[fi]) * 0.125f + mk[c];
            }

        float alpha[4];
        #pragma unroll
        for (int r = 0; r < 4; ++r) {
            float mx = fmaxf(fmaxf(sv[0][r], sv[1][r]), fmaxf(sv[2][r], sv[3][r]));
            #pragma unroll
            for (int off = 1; off < 16; off <<= 1) mx = fmaxf(mx, __shfl_xor(mx, off, 64));
            float mnew = fmaxf(mrow[r], mx);
            alpha[r] = __expf(mrow[r] - mnew);
            mrow[r] = mnew;
            float rs = 0.f;
            #pragma unroll
            for (int c = 0; c < 4; ++c) {
                float p = __expf(sv[c][r] - mnew);
                sv[c][r] = p;
                rs += p;
            }
            #pragma unroll
            for (int off = 1; off < 16; off <<= 1) rs += __shfl_xor(rs, off, 64);
            lrow[r] = lrow[r] * alpha[r] + rs;
            o[0][r] *= alpha[r]; o[1][r] *= alpha[r]; o[2][r] *= alpha[r]; o[3][r] *= alpha[r];
        }

        #pragma unroll
        for (int c = 0; c < 4; ++c)
            #pragma unroll
            for (int r = 0; r < 4; ++r)
                Pw[(quad * 4 + r) * 72 + c * 16 + l15] = f2b(sv[c][r]);

        bf16x8 pf0 = *(const bf16x8*)&Pw[l15 * 72 + quad * 8];
        bf16x8 pf1 = *(const bf16x8*)&Pw[l15 * 72 + 32 + quad * 8];

        #pragma unroll
        for (int dt = 0; dt < 4; ++dt) {
            int row = dt * 16 + l15;
            bf16x8 v0f = *(const bf16x8*)&cV[row * 64 + (quad ^ l7) * 8];
            bf16x8 v1f = *(const bf16x8*)&cV[row * 64 + ((quad + 4) ^ l7) * 8];
            o[dt] = __builtin_amdgcn_mfma_f32_16x16x32_bf16(pf0, v0f, o[dt], 0, 0, 0);
            o[dt] = __builtin_amdgcn_mfma_f32_16x16x32_bf16(pf1, v1f, o[dt], 0, 0, 0);
        }

        __syncthreads();
    }

    const float hm = hmask[h];
    #pragma unroll
    for (int r = 0; r < 4; ++r) {
        float inv = hm / lrow[r];
        int s = m0w + quad * 4 + r;
        float* op = out + ((size_t)(b * SS + s)) * HIDD + h * DH;
        #pragma unroll
        for (int dt = 0; dt < 4; ++dt) op[dt * 16 + l15] = o[dt][r] * inv;
    }
}

extern "C" void kernel_launch(void* const* d_in, const int* in_sizes, int n_in,
                              void* d_out, int out_size, void* d_ws, size_t ws_size,
                              hipStream_t stream) {
    const float* hs    = (const float*)d_in[0];
    const float* am    = (const float*)d_in[1];
    const float* hm    = (const float*)d_in[2];
    const float* rel   = (const float*)d_in[3];
    const float* rel2d = (const float*)d_in[4];
    const float* Wq    = (const float*)d_in[5];
    const float* bq    = (const float*)d_in[6];
    const float* Wk    = (const float*)d_in[7];
    const float* bk    = (const float*)d_in[8];
    const float* Wv    = (const float*)d_in[9];
    const float* bv    = (const float*)d_in[10];
    float* out = (float*)d_out;

    unsigned short* Xb  = (unsigned short*)d_ws;              // 2048*768
    unsigned short* Wt  = Xb + 2048 * HIDD;                   // 3*768*768
    unsigned short* Qh  = Wt + 3 * HIDD * HIDD;               // 24*1024*64 each
    unsigned short* Kh  = Qh + (size_t)BH * SS * DH;
    unsigned short* Vh  = Kh + (size_t)BH * SS * DH;
    unsigned short* VhT = Vh + (size_t)BH * SS * DH;
    _Float16* Bh = (_Float16*)(VhT + (size_t)BH * SS * DH);   // 24*1024*1024 fp16

    // workspace audit: base = Xb 3,145,728 + Wt 3,538,944 + 4x 3,145,728
    //                       = 19,267,584 B; Bh adds 50,331,648 B.
    const size_t WS_NEEDED = 19267584ULL + 50331648ULL;       // 69,599,232
    const bool use_prep = (ws_size >= WS_NEEDED);

    if (use_prep)
        prep_bias<<<3072, 256, 0, stream>>>(rel, rel2d, am, Bh);
    cvt_x<<<(2048 * HIDD / 4) / 256, 256, 0, stream>>>(hs, Xb);
    dim3 gT(24, 24, 3);
    transpose_w<<<gT, 256, 0, stream>>>(Wq, Wk, Wv, Wt);
    dim3 gG(16, 36);
    qkv_gemm<<<gG, 256, 0, stream>>>(Xb, Wt, bq, bk, bv, Qh, Kh, Vh);
    dim3 gV(16, BH);
    transpose_v<<<gV, 256, 0, stream>>>(Vh, VhT);
    dim3 gF(32, BH);
    if (use_prep)
        flash_attn_pb<<<gF, 128, 0, stream>>>(Qh, Kh, VhT, Bh, hm, out);
    else
        flash_attn_v0<<<gF, 128, 0, stream>>>(Qh, Kh, VhT, rel, rel2d, am, hm, out);
}

// Round 10
// 280.152 us; speedup vs baseline: 1.1082x; 1.1082x over previous
//
#include <hip/hip_runtime.h>
#include <hip/hip_bf16.h>
#include <cstdint>

#define BB   2
#define SS   1024
#define HIDD 768
#define NH   12
#define DH   64
#define BH   (BB*NH)   // 24

typedef short bf16x8 __attribute__((ext_vector_type(8)));
typedef float f32x4  __attribute__((ext_vector_type(4)));

__device__ __forceinline__ unsigned short f2b(float x) {
    union { float f; uint32_t u; } v; v.f = x;
    uint32_t u = v.u;
    uint32_t r = (u + 0x7fffu + ((u >> 16) & 1u)) >> 16;
    return (unsigned short)r;
}

__device__ __forceinline__ void async16(const void* g, void* l) {
    __builtin_amdgcn_global_load_lds(
        (const __attribute__((address_space(1))) unsigned int*)g,
        (__attribute__((address_space(3))) unsigned int*)l,
        16, 0, 0);
}

// ---------------- kernel 1: hidden_states fp32 -> bf16 ----------------
__global__ void cvt_x(const float* __restrict__ x, unsigned short* __restrict__ xb) {
    int i = blockIdx.x * blockDim.x + threadIdx.x;   // one float4 per thread
    float4 v = ((const float4*)x)[i];
    ushort4 o;
    o.x = f2b(v.x); o.y = f2b(v.y); o.z = f2b(v.z); o.w = f2b(v.w);
    ((ushort4*)xb)[i] = o;
}

// ------------- kernel 2: W [k][n] fp32 -> Wt [n][k] bf16 (q|k|v) -------------
__global__ void transpose_w(const float* __restrict__ Wq, const float* __restrict__ Wk,
                            const float* __restrict__ Wv, unsigned short* __restrict__ Wt) {
    __shared__ float tile[32][33];
    const int w = blockIdx.z;
    const float* W = (w == 0) ? Wq : (w == 1) ? Wk : Wv;
    const int tx = threadIdx.x & 31, ty = threadIdx.x >> 5;   // 32 x 8
    const int k0 = blockIdx.x * 32, n0 = blockIdx.y * 32;
    for (int p = 0; p < 4; ++p)
        tile[ty + p * 8][tx] = W[(k0 + ty + p * 8) * HIDD + n0 + tx];
    __syncthreads();
    for (int p = 0; p < 4; ++p) {
        int n = n0 + ty + p * 8;
        Wt[(w * HIDD + n) * HIDD + k0 + tx] = f2b(tile[tx][ty + p * 8]);
    }
}

// ------------- kernel 3: QKV GEMM 2048x2304x768, bf16 MFMA -------------
// v9 (resubmit: round-9 bench was a container/infra failure, no verdict;
// audit: V-store is 8B-aligned, in-bounds, workspace SMALLER than v0's):
// the V section (n0 >= 1536) is written DIRECTLY in transposed layout
// VhT[bh][d][s]. Per (i,j) fragment a lane's 4 accumulator regs are 4
// CONSECUTIVE s at fixed d -> one packed 8B ushort4 store. This deletes the
// separate transpose_v kernel (12.6 MB re-read/re-write + a launch).
__global__ __launch_bounds__(256) void qkv_gemm(
    const unsigned short* __restrict__ Xb, const unsigned short* __restrict__ Wt,
    const float* __restrict__ bq, const float* __restrict__ bk, const float* __restrict__ bv,
    unsigned short* __restrict__ Qh, unsigned short* __restrict__ Kh,
    unsigned short* __restrict__ VhT) {
    __shared__ __align__(16) unsigned short lA[2][128 * 32];
    __shared__ __align__(16) unsigned short lB[2][64 * 32];
    const int t = threadIdx.x;
    const int wave = t >> 6, lane = t & 63;
    const int l15 = lane & 15, quad = lane >> 4;
    const int m0 = blockIdx.x * 128;
    const int n0 = blockIdx.y * 64;
    const int wm = wave * 32;

    f32x4 acc[2][4] = {};

    auto stage = [&](int k0, int b) {
        #pragma unroll
        for (int r = 0; r < 2; ++r) {
            int ci = r * 256 + t;
            async16(Xb + (m0 + (ci >> 2)) * HIDD + k0 + (ci & 3) * 8,
                    &lA[b][(r * 256 + wave * 64) * 8]);
        }
        async16(Wt + (n0 + (t >> 2)) * HIDD + k0 + (t & 3) * 8,
                &lB[b][(wave * 64) * 8]);
    };

    stage(0, 0);
    for (int ki = 0; ki < 24; ++ki) {
        const int cur = ki & 1;
        __syncthreads();
        if (ki < 23) stage((ki + 1) * 32, cur ^ 1);
        bf16x8 af[2], bf[4];
        #pragma unroll
        for (int i = 0; i < 2; ++i)
            af[i] = *(const bf16x8*)&lA[cur][(wm + i * 16 + l15) * 32 + quad * 8];
        #pragma unroll
        for (int j = 0; j < 4; ++j)
            bf[j] = *(const bf16x8*)&lB[cur][(j * 16 + l15) * 32 + quad * 8];
        #pragma unroll
        for (int i = 0; i < 2; ++i)
            #pragma unroll
            for (int j = 0; j < 4; ++j)
                acc[i][j] = __builtin_amdgcn_mfma_f32_16x16x32_bf16(af[i], bf[j], acc[i][j], 0, 0, 0);
    }

    const int sect = (n0 >= 1536) ? 2 : (n0 >= 768) ? 1 : 0;
    if (sect == 2) {
        // ---- V: direct transposed write, packed 8B stores ----
        #pragma unroll
        for (int i = 0; i < 2; ++i) {
            int m = m0 + wm + i * 16 + quad * 4;       // s base (mult of 4)
            int bb = m >> 10, s = m & 1023;
            #pragma unroll
            for (int j = 0; j < 4; ++j) {
                int nn = n0 + j * 16 + l15 - 1536;
                int h = nn >> 6, d = nn & 63;
                float bval = bv[nn];
                ushort4 pv;
                pv.x = f2b(acc[i][j][0] + bval);
                pv.y = f2b(acc[i][j][1] + bval);
                pv.z = f2b(acc[i][j][2] + bval);
                pv.w = f2b(acc[i][j][3] + bval);
                *(ushort4*)&VhT[((size_t)(bb * NH + h) * DH + d) * SS + s] = pv;
            }
        }
    } else {
        const float* bias = (sect == 0) ? bq : bk;
        unsigned short* dst = (sect == 0) ? Qh : Kh;
        const float scale = (sect == 0) ? 0.125f : 1.0f;
        #pragma unroll
        for (int i = 0; i < 2; ++i) {
            #pragma unroll
            for (int j = 0; j < 4; ++j) {
                int n  = n0 + j * 16 + l15;
                int nn = n - sect * HIDD;
                int h = nn >> 6, d = nn & 63;
                float bval = bias[nn];
                #pragma unroll
                for (int r = 0; r < 4; ++r) {
                    int m = m0 + wm + i * 16 + quad * 4 + r;
                    int b = m >> 10, s = m & 1023;
                    float v = (acc[i][j][r] + bval) * scale;
                    dst[((size_t)(b * NH + h) * SS + s) * DH + d] = f2b(v);
                }
            }
        }
    }
}

// ------------- kernel 4: flash attention (v0, best measured) -------------
// Exact round-0 structure: LDS-resident double-buffered K/V + per-iteration
// bias staging + full-drain barriers. Across v2-v8 every alternative
// (reg-prefetch, depth-2 counted vmcnt, 1KB bursts, split-K 35% occupancy,
// XCD colocation, fp16 pre-compression) was measured equal or worse.
// Evidence (r8): a pure-streaming kernel on this environment tops out at
// ~2.8 TB/s effective; this kernel's 201 MB bias read at ~2.2 TB/s effective
// is within ~20% of that machine cap -> bias-read floor ~= 90 us.
__global__ __launch_bounds__(128) void flash_attn(
    const unsigned short* __restrict__ Qh, const unsigned short* __restrict__ Kh,
    const unsigned short* __restrict__ VhT,
    const float* __restrict__ rel, const float* __restrict__ rel2d,
    const float* __restrict__ amask, const float* __restrict__ hmask,
    float* __restrict__ out) {
    // [0,16384)  lK[2] (2 x 64x64 bf16, swizzled)
    // [16384,32768) lV[2]
    // [32768,49152) bias: wave w at +w*8192 (stgA 4KB | stgB 4KB)
    // [49152,53760) P: wave w at +w*2304 (16x72 bf16)
    __shared__ __align__(16) char smemraw[53760];

    const int t = threadIdx.x;
    const int wave = t >> 6, lane = t & 63;
    const int l15 = lane & 15, quad = lane >> 4;
    const int l7 = l15 & 7;
    const int bh = blockIdx.y;
    const int b = bh / NH, h = bh % NH;
    const int m0w = blockIdx.x * 32 + wave * 16;

    const unsigned short* Qp = Qh + (size_t)bh * SS * DH;
    const unsigned short* Kp = Kh + (size_t)bh * SS * DH;
    const unsigned short* Vp = VhT + (size_t)bh * DH * SS;
    const float* relp  = rel   + (size_t)bh * SS * SS;
    const float* rel2p = rel2d + (size_t)bh * SS * SS;
    const float* maskp = amask + (size_t)b * SS;

    float* stgA = (float*)(smemraw + 32768 + wave * 8192);
    float* stgB = stgA + 1024;
    unsigned short* Pw = (unsigned short*)(smemraw + 49152) + wave * (16 * 72);

    auto stage_kv = [&](int j0, int buf) {
        unsigned short* dK = (unsigned short*)(smemraw + buf * 8192);
        unsigned short* dV = (unsigned short*)(smemraw + 16384 + buf * 8192);
        #pragma unroll
        for (int i = 0; i < 4; ++i) {
            int ci = i * 128 + t;                 // 0..511
            int row = ci >> 3, sc = ci & 7;
            int g = sc ^ (row & 7);               // fetch-side XOR swizzle
            async16(Kp + (size_t)(j0 + row) * DH + g * 8,
                    dK + (i * 128 + wave * 64) * 8);
            async16(Vp + (size_t)row * SS + j0 + g * 8,
                    dV + (i * 128 + wave * 64) * 8);
        }
    };

    auto stage_bias = [&](int j0) {
        #pragma unroll
        for (int i = 0; i < 4; ++i) {
            async16(relp  + (size_t)(m0w + 4 * i + quad) * SS + j0 + l15 * 4,
                    (char*)stgA + i * 1024);
            async16(rel2p + (size_t)(m0w + 4 * i + quad) * SS + j0 + l15 * 4,
                    (char*)stgB + i * 1024);
        }
    };

    bf16x8 qf0 = *(const bf16x8*)&Qp[(m0w + l15) * DH + quad * 8];
    bf16x8 qf1 = *(const bf16x8*)&Qp[(m0w + l15) * DH + 32 + quad * 8];

    f32x4 o[4] = {};
    float mrow[4] = {-1e30f, -1e30f, -1e30f, -1e30f};
    float lrow[4] = {0.f, 0.f, 0.f, 0.f};

    stage_kv(0, 0);
    __syncthreads();   // drains tile-0 staging

    for (int tt = 0; tt < 16; ++tt) {
        const int j0 = tt * 64, cur = tt & 1;
        const unsigned short* cK = (const unsigned short*)(smemraw + cur * 8192);
        const unsigned short* cV = (const unsigned short*)(smemraw + 16384 + cur * 8192);

        // ---- issue: bias (oldest 8) then next K/V (8) ----
        stage_bias(j0);
        if (tt < 15) stage_kv(j0 + 64, cur ^ 1);

        float mk[4];
        #pragma unroll
        for (int c = 0; c < 4; ++c) mk[c] = maskp[j0 + c * 16 + l15];

        // ---- QK^T from LDS buf[cur] (drained by previous barrier) ----
        f32x4 sc4[4] = {};
        #pragma unroll
        for (int c = 0; c < 4; ++c) {
            int row = c * 16 + l15;
            bf16x8 k0f = *(const bf16x8*)&cK[row * 64 + (quad ^ l7) * 8];
            bf16x8 k1f = *(const bf16x8*)&cK[row * 64 + ((quad + 4) ^ l7) * 8];
            sc4[c] = __builtin_amdgcn_mfma_f32_16x16x32_bf16(qf0, k0f, sc4[c], 0, 0, 0);
            sc4[c] = __builtin_amdgcn_mfma_f32_16x16x32_bf16(qf1, k1f, sc4[c], 0, 0, 0);
        }

        // ---- drain bias (first-issued 8 of >=16 outstanding) ----
        if (tt < 15) { asm volatile("s_waitcnt vmcnt(8)" ::: "memory"); }
        else         { asm volatile("s_waitcnt vmcnt(0)" ::: "memory"); }

        // ---- bias add in C layout ----
        float sv[4][4];
        #pragma unroll
        for (int c = 0; c < 4; ++c)
            #pragma unroll
            for (int r = 0; r < 4; ++r) {
                int fi = (quad * 4 + r) * 64 + c * 16 + l15;
                sv[c][r] = sc4[c][r] + (stgA[fi] + stgB[fi]) * 0.125f + mk[c];
            }

        // ---- online softmax per row (reg r <-> row quad*4+r) ----
        float alpha[4];
        #pragma unroll
        for (int r = 0; r < 4; ++r) {
            float mx = fmaxf(fmaxf(sv[0][r], sv[1][r]), fmaxf(sv[2][r], sv[3][r]));
            #pragma unroll
            for (int off = 1; off < 16; off <<= 1) mx = fmaxf(mx, __shfl_xor(mx, off, 64));
            float mnew = fmaxf(mrow[r], mx);
            alpha[r] = __expf(mrow[r] - mnew);
            mrow[r] = mnew;
            float rs = 0.f;
            #pragma unroll
            for (int c = 0; c < 4; ++c) {
                float p = __expf(sv[c][r] - mnew);
                sv[c][r] = p;
                rs += p;
            }
            #pragma unroll
            for (int off = 1; off < 16; off <<= 1) rs += __shfl_xor(rs, off, 64);
            lrow[r] = lrow[r] * alpha[r] + rs;
            o[0][r] *= alpha[r]; o[1][r] *= alpha[r]; o[2][r] *= alpha[r]; o[3][r] *= alpha[r];
        }

        // ---- P -> LDS (A-operand layout) ----
        #pragma unroll
        for (int c = 0; c < 4; ++c)
            #pragma unroll
            for (int r = 0; r < 4; ++r)
                Pw[(quad * 4 + r) * 72 + c * 16 + l15] = f2b(sv[c][r]);

        bf16x8 pf0 = *(const bf16x8*)&Pw[l15 * 72 + quad * 8];
        bf16x8 pf1 = *(const bf16x8*)&Pw[l15 * 72 + 32 + quad * 8];

        // ---- O += P . V from LDS buf[cur] ----
        #pragma unroll
        for (int dt = 0; dt < 4; ++dt) {
            int row = dt * 16 + l15;
            bf16x8 v0f = *(const bf16x8*)&cV[row * 64 + (quad ^ l7) * 8];
            bf16x8 v1f = *(const bf16x8*)&cV[row * 64 + ((quad + 4) ^ l7) * 8];
            o[dt] = __builtin_amdgcn_mfma_f32_16x16x32_bf16(pf0, v0f, o[dt], 0, 0, 0);
            o[dt] = __builtin_amdgcn_mfma_f32_16x16x32_bf16(pf1, v1f, o[dt], 0, 0, 0);
        }

        __syncthreads();   // buf[cur] free for overwrite; drains in-flight KV
    }

    // ---- epilogue: each wave owns its rows, no combine ----
    const float hm = hmask[h];
    #pragma unroll
    for (int r = 0; r < 4; ++r) {
        float inv = hm / lrow[r];
        int s = m0w + quad * 4 + r;
        float* op = out + ((size_t)(b * SS + s)) * HIDD + h * DH;
        #pragma unroll
        for (int dt = 0; dt < 4; ++dt) op[dt * 16 + l15] = o[dt][r] * inv;
    }
}

extern "C" void kernel_launch(void* const* d_in, const int* in_sizes, int n_in,
                              void* d_out, int out_size, void* d_ws, size_t ws_size,
                              hipStream_t stream) {
    const float* hs    = (const float*)d_in[0];
    const float* am    = (const float*)d_in[1];
    const float* hm    = (const float*)d_in[2];
    const float* rel   = (const float*)d_in[3];
    const float* rel2d = (const float*)d_in[4];
    const float* Wq    = (const float*)d_in[5];
    const float* bq    = (const float*)d_in[6];
    const float* Wk    = (const float*)d_in[7];
    const float* bk    = (const float*)d_in[8];
    const float* Wv    = (const float*)d_in[9];
    const float* bv    = (const float*)d_in[10];
    float* out = (float*)d_out;

    unsigned short* Xb  = (unsigned short*)d_ws;              // 2048*768
    unsigned short* Wt  = Xb + 2048 * HIDD;                   // 3*768*768
    unsigned short* Qh  = Wt + 3 * HIDD * HIDD;               // 24*1024*64 each
    unsigned short* Kh  = Qh + (size_t)BH * SS * DH;
    unsigned short* VhT = Kh + (size_t)BH * SS * DH;          // [bh][d][s]

    cvt_x<<<(2048 * HIDD / 4) / 256, 256, 0, stream>>>(hs, Xb);
    dim3 gT(24, 24, 3);
    transpose_w<<<gT, 256, 0, stream>>>(Wq, Wk, Wv, Wt);
    dim3 gG(16, 36);
    qkv_gemm<<<gG, 256, 0, stream>>>(Xb, Wt, bq, bk, bv, Qh, Kh, VhT);
    dim3 gF(32, BH);
    flash_attn<<<gF, 128, 0, stream>>>(Qh, Kh, VhT, rel, rel2d, am, hm, out);
}